// Round 10
// baseline (232.138 us; speedup 1.0000x reference)
//
#include <hip/hip_runtime.h>

// Wavelet_Convolution: out = relu(phi1 @ (kernel * (phi0 @ (x @ W))))
// N=100000, F=128, NNZ=1.6M per sparse matrix (COO, int32 idx, f32 vals).
//
// Pipeline (5 dispatches):
//   1) transpose_w: Wt = bf16(W^T)
//   2) gemm_mfma:   X'(bf16) = x @ W   (MFMA, A-tile LDS, B from global)
//   3) bucket_scatter: per 7168-edge chunk, group records by 256-row bucket
//      in LDS, flush block-contiguous (perfectly coalesced, no global
//      atomics, no write amplification). Run directory (u16) per
//      (block,bucket) records run offsets.
//   4) sort_spmm<phi0>: per bucket: read its 224 runs, LDS counting-sort by
//      local row, 4-wide bf16 gather-SpMM, fused kernel-scale -> Xt(bf16)
//   5) sort_spmm<phi1>: same, fused relu -> out(f32)

constexpr int kN = 100000;
constexpr int kF = 128;
constexpr int kNNZ = 1600000;

constexpr int kBuckets = (kN + 255) / 256;                  // 391 (256-row buckets)
constexpr int kBucketCap = 4608;                            // mean 4096 + 8 sigma
constexpr int kChunk = 7168;                                // edges per scatter block
constexpr int kChunkBlocks = (kNNZ + kChunk - 1) / kChunk;  // 224 per matrix
constexpr int kSlotsPerMat = kChunkBlocks * kChunk;         // 1,605,632
constexpr int kDirStride = kBuckets + 1;                    // 392 entries per block
constexpr int kGemmBlocks = (kN + 63) / 64;                 // 1563

typedef short bf16x8 __attribute__((ext_vector_type(8)));
typedef float f32x4 __attribute__((ext_vector_type(4)));
typedef unsigned short ushort4v __attribute__((ext_vector_type(4)));

__device__ __forceinline__ unsigned short f32_to_bf16(float f) {
    unsigned int u = __float_as_uint(f);
    u += 0x7fffu + ((u >> 16) & 1u);   // round-to-nearest-even
    return (unsigned short)(u >> 16);
}
__device__ __forceinline__ float bf16_to_f32(unsigned short h) {
    return __uint_as_float((unsigned int)h << 16);
}

// ---------------------------------------------------------------------------
// Wt[n][k] = bf16(W[k][n])
// ---------------------------------------------------------------------------
__global__ __launch_bounds__(256) void transpose_w(const float* __restrict__ W,
                                                   unsigned short* __restrict__ Wt) {
    const int e = blockIdx.x * 256 + threadIdx.x;   // grid 64
    const int n = e & 127, k = e >> 7;
    Wt[n * 128 + k] = f32_to_bf16(W[e]);
}

// ---------------------------------------------------------------------------
// GEMM: X'(bf16) = x @ W via mfma_f32_16x16x32_bf16 (verified r2-r9).
// A-tile in LDS (swizzled); B-fragments from global Wt (L1-resident).
// ---------------------------------------------------------------------------
__global__ __launch_bounds__(256) void gemm_mfma(const float* __restrict__ x,
                                                 const unsigned short* __restrict__ Wt,
                                                 unsigned short* __restrict__ Xpb) {
    __shared__ __align__(16) unsigned short xs[64 * 128];   // 16 KB
    const int t = threadIdx.x;
    const int rowBase = blockIdx.x * 64;

    {
        const int lrow = t >> 2;
        const int q = t & 3;
        int srow = rowBase + lrow;
        if (srow >= kN) srow = kN - 1;
        const float4* xr = (const float4*)(x + (size_t)srow * kF) + q * 8;
        #pragma unroll
        for (int i = 0; i < 8; ++i) {
            const float4 f = xr[i];
            ushort4v h;
            h.x = f32_to_bf16(f.x); h.y = f32_to_bf16(f.y);
            h.z = f32_to_bf16(f.z); h.w = f32_to_bf16(f.w);
            const int kidx = q * 32 + i * 4;
            *(ushort4v*)&xs[lrow * 128 + (kidx ^ ((lrow & 7) << 3))] = h;
        }
    }
    __syncthreads();

    const int w = t >> 6;
    const int l = t & 63;
    const int lr = l & 15;
    const int lq = l >> 4;

    f32x4 acc[8];
    #pragma unroll
    for (int n = 0; n < 8; ++n) acc[n] = (f32x4){0.f, 0.f, 0.f, 0.f};

    const int arow = w * 16 + lr;
    #pragma unroll
    for (int ks = 0; ks < 4; ++ks) {
        const int akidx = ks * 32 + lq * 8;
        const bf16x8 a = *(const bf16x8*)&xs[arow * 128 + (akidx ^ ((arow & 7) << 3))];
        #pragma unroll
        for (int n = 0; n < 8; ++n) {
            const int bn = n * 16 + lr;
            const bf16x8 b = *(const bf16x8*)(Wt + bn * 128 + akidx);  // global, L1
            acc[n] = __builtin_amdgcn_mfma_f32_16x16x32_bf16(a, b, acc[n], 0, 0, 0);
        }
    }

    // C/D layout: col = lr, row = lq*4 + j
    #pragma unroll
    for (int j = 0; j < 4; ++j) {
        const int row = rowBase + w * 16 + lq * 4 + j;
        if (row < kN) {
            unsigned short* orow = Xpb + (size_t)row * kF + lr;
            #pragma unroll
            for (int n = 0; n < 8; ++n) orow[n * 16] = f32_to_bf16(acc[n][j]);
        }
    }
}

// ---------------------------------------------------------------------------
// bucket_scatter: one block per 7168-edge chunk (both matrices, grid 448).
// Group the chunk's records by 256-row bucket in LDS, flush the whole chunk
// block-contiguous (fully coalesced). Record: hi32 = f32 val,
// lo32 = (localrow&255)<<17 | col. Run directory: dir[b][bk] = local offset
// (u16) of bucket bk's run within the chunk; entry 391 = total count.
// LDS: 56KB recs + ~5.6KB tables = 61.6 KB.
// ---------------------------------------------------------------------------
__global__ __launch_bounds__(256) void bucket_scatter(
    const int* __restrict__ r0, const int* __restrict__ c0, const float* __restrict__ v0,
    const int* __restrict__ r1, const int* __restrict__ c1, const float* __restrict__ v1,
    unsigned long long* __restrict__ stg, unsigned short* __restrict__ dir) {
    __shared__ unsigned long long recs[kChunk];   // 56 KB
    __shared__ int hist[kDirStride];
    __shared__ int loff[kDirStride];
    __shared__ int cur[kDirStride];
    __shared__ int sc2[256];

    const int b = blockIdx.x;
    const bool m1 = b >= kChunkBlocks;
    const int cb = m1 ? b - kChunkBlocks : b;
    const int* rows = m1 ? r1 : r0;
    const int* cols = m1 ? c1 : c0;
    const float* vals = m1 ? v1 : v0;
    unsigned long long* dst = stg + (size_t)b * kChunk;      // block-contiguous
    unsigned short* dirm = dir + (size_t)b * kDirStride;

    const int t = threadIdx.x;
    for (int i = t; i < kDirStride; i += 256) hist[i] = 0;
    __syncthreads();

    const int base0 = cb * kChunk;
    // pass 1: histogram by bucket
    for (int j = t; j < kChunk; j += 256) {
        const int idx = base0 + j;
        if (idx < kNNZ) atomicAdd(&hist[rows[idx] >> 8], 1);
    }
    __syncthreads();

    // pass 2: scan 392 bins (threads 0..195 own bins 2t, 2t+1)
    int s = 0;
    if (t < 196) s = hist[2 * t] + hist[2 * t + 1];
    sc2[t] = (t < 196) ? s : 0;
    __syncthreads();
    #pragma unroll
    for (int off = 1; off < 256; off <<= 1) {
        const int add = (t >= off) ? sc2[t - off] : 0;
        __syncthreads();
        sc2[t] += add;
        __syncthreads();
    }
    if (t < 196) {
        const int ex = sc2[t] - s;
        loff[2 * t] = ex;             loff[2 * t + 1] = ex + hist[2 * t];
        cur[2 * t] = ex;              cur[2 * t + 1] = ex + hist[2 * t];
        dirm[2 * t] = (unsigned short)ex;
        dirm[2 * t + 1] = (unsigned short)(ex + hist[2 * t]);
    }
    __syncthreads();

    // pass 3: place records grouped by bucket in LDS
    for (int j = t; j < kChunk; j += 256) {
        const int idx = base0 + j;
        if (idx < kNNZ) {
            const int r = rows[idx];
            const int bk = r >> 8;
            const int pos = atomicAdd(&cur[bk], 1);
            const unsigned int key =
                ((unsigned int)(r & 255) << 17) | (unsigned int)cols[idx];
            recs[pos] = ((unsigned long long)__float_as_uint(vals[idx]) << 32) | key;
        }
    }
    __syncthreads();

    // pass 4: flush whole chunk, perfectly coalesced (tail slots unread)
    for (int j = t; j < kChunk; j += 256) dst[j] = recs[j];
}

// ---------------------------------------------------------------------------
// sort_spmm: one 512-thread block per 256-row bucket.
//   a) read run dir (224 runs) -> rlen/gst
//   b) histogram records by local row (ragged global run reads)
//   c) scan 256 bins
//   d) place records into LDS sorted by local row
//   e) per-row 4-wide bf16 gather-SpMM; fused scale / relu.
// LDS: 36.9KB sorted + ~5.5KB tables = 42.4 KB -> 3 blocks/CU.
// ---------------------------------------------------------------------------
template <bool ROW_SCALE, bool RELU, bool OUT_BF16>
__global__ __launch_bounds__(512) void sort_spmm(
    const unsigned long long* __restrict__ stg,   // this matrix's slots
    const unsigned short* __restrict__ dir,       // this matrix's directory
    const float* __restrict__ scale,
    const unsigned short* __restrict__ Xin,
    void* __restrict__ Xout) {
    __shared__ unsigned long long sorted[kBucketCap];   // 36.9 KB
    __shared__ int rlen[kChunkBlocks];                  // 224
    __shared__ int gst[kChunkBlocks];
    __shared__ int hist[256];
    __shared__ int sc[256];
    __shared__ int cur[256];

    const int bk = blockIdx.x;
    const int t = threadIdx.x;

    // a) run directory
    if (t < kChunkBlocks) {
        const unsigned short* dd = dir + (size_t)t * kDirStride;
        const int s = dd[bk];
        rlen[t] = dd[bk + 1] - s;
        gst[t] = t * kChunk + s;
    }
    if (t < 256) hist[t] = 0;
    __syncthreads();

    const int g = t >> 5;        // 16 groups
    const int lane = t & 31;

    // b) histogram by local row
    for (int blk = g; blk < kChunkBlocks; blk += 16) {
        const int len = rlen[blk];
        const int gs = gst[blk];
        for (int i = lane; i < len; i += 32) {
            const unsigned int lo = (unsigned int)stg[gs + i];
            atomicAdd(&hist[(lo >> 17) & 255], 1);
        }
    }
    __syncthreads();

    // c) scan 256 bins
    const int v = (t < 256) ? hist[t] : 0;
    if (t < 256) sc[t] = v;
    __syncthreads();
    #pragma unroll
    for (int off = 1; off < 256; off <<= 1) {
        const int add = (t < 256 && t >= off) ? sc[t - off] : 0;
        __syncthreads();
        if (t < 256) sc[t] += add;
        __syncthreads();
    }
    if (t < 256) cur[t] = sc[t] - v;   // exclusive
    __syncthreads();

    // d) place sorted by local row
    for (int blk = g; blk < kChunkBlocks; blk += 16) {
        const int len = rlen[blk];
        const int gs = gst[blk];
        for (int i = lane; i < len; i += 32) {
            const unsigned long long p = stg[gs + i];
            const int lr = (int)(((unsigned int)p >> 17) & 255);
            sorted[atomicAdd(&cur[lr], 1)] = p;
        }
    }
    __syncthreads();

    // e) gather SpMM: 16 groups x 32 lanes; each group handles 16 rows
    for (int i = 0; i < 16; ++i) {
        const int lr = g * 16 + i;
        const int row = bk * 256 + lr;
        if (row >= kN) continue;
        const int e = sc[lr];
        const int s0 = e - hist[lr];

        float4 acc = make_float4(0.f, 0.f, 0.f, 0.f);
        int j = s0;
        for (; j + 4 <= e; j += 4) {
            const unsigned long long p0 = sorted[j];
            const unsigned long long p1 = sorted[j + 1];
            const unsigned long long p2 = sorted[j + 2];
            const unsigned long long p3 = sorted[j + 3];
            const int cc0 = (int)((unsigned int)p0 & 0x1FFFF);
            const int cc1 = (int)((unsigned int)p1 & 0x1FFFF);
            const int cc2 = (int)((unsigned int)p2 & 0x1FFFF);
            const int cc3 = (int)((unsigned int)p3 & 0x1FFFF);
            const float w0 = __uint_as_float((unsigned int)(p0 >> 32));
            const float w1 = __uint_as_float((unsigned int)(p1 >> 32));
            const float w2 = __uint_as_float((unsigned int)(p2 >> 32));
            const float w3 = __uint_as_float((unsigned int)(p3 >> 32));
            const ushort4v x0 = *(const ushort4v*)(Xin + (size_t)cc0 * kF + lane * 4);
            const ushort4v x1 = *(const ushort4v*)(Xin + (size_t)cc1 * kF + lane * 4);
            const ushort4v x2 = *(const ushort4v*)(Xin + (size_t)cc2 * kF + lane * 4);
            const ushort4v x3 = *(const ushort4v*)(Xin + (size_t)cc3 * kF + lane * 4);
            acc.x = fmaf(w0, bf16_to_f32(x0.x), acc.x);
            acc.y = fmaf(w0, bf16_to_f32(x0.y), acc.y);
            acc.z = fmaf(w0, bf16_to_f32(x0.z), acc.z);
            acc.w = fmaf(w0, bf16_to_f32(x0.w), acc.w);
            acc.x = fmaf(w1, bf16_to_f32(x1.x), acc.x);
            acc.y = fmaf(w1, bf16_to_f32(x1.y), acc.y);
            acc.z = fmaf(w1, bf16_to_f32(x1.z), acc.z);
            acc.w = fmaf(w1, bf16_to_f32(x1.w), acc.w);
            acc.x = fmaf(w2, bf16_to_f32(x2.x), acc.x);
            acc.y = fmaf(w2, bf16_to_f32(x2.y), acc.y);
            acc.z = fmaf(w2, bf16_to_f32(x2.z), acc.z);
            acc.w = fmaf(w2, bf16_to_f32(x2.w), acc.w);
            acc.x = fmaf(w3, bf16_to_f32(x3.x), acc.x);
            acc.y = fmaf(w3, bf16_to_f32(x3.y), acc.y);
            acc.z = fmaf(w3, bf16_to_f32(x3.z), acc.z);
            acc.w = fmaf(w3, bf16_to_f32(x3.w), acc.w);
        }
        for (; j < e; ++j) {
            const unsigned long long p = sorted[j];
            const int cc = (int)((unsigned int)p & 0x1FFFF);
            const float wv = __uint_as_float((unsigned int)(p >> 32));
            const ushort4v xv = *(const ushort4v*)(Xin + (size_t)cc * kF + lane * 4);
            acc.x = fmaf(wv, bf16_to_f32(xv.x), acc.x);
            acc.y = fmaf(wv, bf16_to_f32(xv.y), acc.y);
            acc.z = fmaf(wv, bf16_to_f32(xv.z), acc.z);
            acc.w = fmaf(wv, bf16_to_f32(xv.w), acc.w);
        }

        if (ROW_SCALE) {
            const float k = scale[row];
            acc.x *= k; acc.y *= k; acc.z *= k; acc.w *= k;
        }
        if (RELU) {
            acc.x = fmaxf(acc.x, 0.f); acc.y = fmaxf(acc.y, 0.f);
            acc.z = fmaxf(acc.z, 0.f); acc.w = fmaxf(acc.w, 0.f);
        }
        if (OUT_BF16) {
            ushort4v o;
            o.x = f32_to_bf16(acc.x); o.y = f32_to_bf16(acc.y);
            o.z = f32_to_bf16(acc.z); o.w = f32_to_bf16(acc.w);
            *(ushort4v*)((unsigned short*)Xout + (size_t)row * kF + lane * 4) = o;
        } else {
            ((float4*)Xout)[(size_t)row * 32 + lane] = acc;
        }
    }
}

extern "C" void kernel_launch(void* const* d_in, const int* in_sizes, int n_in,
                              void* d_out, int out_size, void* d_ws, size_t ws_size,
                              hipStream_t stream) {
    const float* x    = (const float*)d_in[0];
    const float* W    = (const float*)d_in[1];
    const float* kern = (const float*)d_in[2];
    const int*   p0r  = (const int*)d_in[3];
    const int*   p0c  = (const int*)d_in[4];
    const float* p0v  = (const float*)d_in[5];
    const int*   p1r  = (const int*)d_in[6];
    const int*   p1c  = (const int*)d_in[7];
    const float* p1v  = (const float*)d_in[8];
    float* out = (float*)d_out;

    // ws layout (16B-aligned slabs), total ~77.5 MB
    char* w = (char*)d_ws;
    size_t off = 0;
    unsigned short* Xpb = (unsigned short*)(w + off); off += (size_t)kN * kF * 2; // 25.6 MB
    unsigned short* Xtb = (unsigned short*)(w + off); off += (size_t)kN * kF * 2; // 25.6 MB
    unsigned short* Wt = (unsigned short*)(w + off);  off += 128 * 128 * 2;       // 32 KB
    unsigned long long* stg = (unsigned long long*)(w + off);
    off += (size_t)2 * kSlotsPerMat * 8;                                          // 25.7 MB
    unsigned short* dir = (unsigned short*)(w + off);
    off += (size_t)2 * kChunkBlocks * kDirStride * 2;                             // 351 KB

    const unsigned long long* stg1 = stg + kSlotsPerMat;
    const unsigned short* dir1 = dir + (size_t)kChunkBlocks * kDirStride;

    // 1) Wt = bf16(W^T)
    transpose_w<<<64, 256, 0, stream>>>(W, Wt);

    // 2) X'(bf16) = x @ W
    gemm_mfma<<<kGemmBlocks, 256, 0, stream>>>(x, Wt, Xpb);

    // 3) bucket both edge lists (block-contiguous coalesced records + dir)
    bucket_scatter<<<2 * kChunkBlocks, 256, 0, stream>>>(
        p0r, p0c, p0v, p1r, p1c, p1v, stg, dir);

    // 4) Xt(bf16) = kernel * (phi0 @ X')
    sort_spmm<true, false, true><<<kBuckets, 512, 0, stream>>>(
        stg, dir, kern, Xpb, Xtb);

    // 5) out(f32) = relu(phi1 @ Xt)
    sort_spmm<false, true, false><<<kBuckets, 512, 0, stream>>>(
        stg1, dir1, nullptr, Xtb, out);
}

// Round 11
// 214.245 us; speedup vs baseline: 1.0835x; 1.0835x over previous
//
#include <hip/hip_runtime.h>

// Wavelet_Convolution: out = relu(phi1 @ (kernel * (phi0 @ (x @ W))))
// N=100000, F=128, NNZ=1.6M per sparse matrix (COO, int32 idx, f32 vals).
//
// Pipeline (5 dispatches):
//   1) scatter_transpose: [blocks 0..63] Wt = bf16(W^T);
//      [rest] per 7168-edge chunk: group records by 256-row bucket in LDS,
//      flush block-contiguous into d_out-as-scratch (fully coalesced, no
//      global atomics). Run directory (u16) per (chunk,bucket).
//   2) gemm_mfma: X'(bf16) = x @ W  (MFMA; A-tile LDS swizzled, B from L1)
//   3) bucket_sort: per bucket (both matrices, 782 blocks): gather runs,
//      LDS counting-sort by row, flush sorted records to global (coalesced)
//      + absolute per-row [rs,re) bounds.
//   4) spmm_csr: Xt(bf16) = kernel * (phi0 @ X')  — row-parallel gather
//      (12500 blocks, 32 lanes/row, shuffle-broadcast, 4-wide bf16 gathers)
//   5) spmm_csr: out(f32) = relu(phi1 @ Xt) — overwrites the dead scratch.

constexpr int kN = 100000;
constexpr int kF = 128;
constexpr int kNNZ = 1600000;

constexpr int kBuckets = (kN + 255) / 256;                  // 391 (256-row buckets)
constexpr int kBucketCap = 4608;                            // mean 4096 + 8 sigma
constexpr int kChunk = 7168;                                // edges per scatter block
constexpr int kChunkBlocks = (kNNZ + kChunk - 1) / kChunk;  // 224 per matrix
constexpr int kSlotsPerMat = kChunkBlocks * kChunk;         // 1,605,632
constexpr int kDirStride = kBuckets + 1;                    // 392 entries per chunk
constexpr int kGemmBlocks = (kN + 63) / 64;                 // 1563
constexpr int kRowBlocks = kN * 32 / 256;                   // 12500
constexpr int kTransBlocks = 64;

typedef short bf16x8 __attribute__((ext_vector_type(8)));
typedef float f32x4 __attribute__((ext_vector_type(4)));
typedef unsigned short ushort4v __attribute__((ext_vector_type(4)));

__device__ __forceinline__ unsigned short f32_to_bf16(float f) {
    unsigned int u = __float_as_uint(f);
    u += 0x7fffu + ((u >> 16) & 1u);   // round-to-nearest-even
    return (unsigned short)(u >> 16);
}
__device__ __forceinline__ float bf16_to_f32(unsigned short h) {
    return __uint_as_float((unsigned int)h << 16);
}

// ---------------------------------------------------------------------------
// Dispatch 1: W transpose (blocks 0..63) + coalesced bucket scatter (rest).
// Record: hi32 = f32 val, lo32 = (localrow&255)<<17 | col (col < 2^17).
// dir[chunk][bk] = u16 offset of bucket bk's run within the chunk;
// entry 391 = chunk total.
// ---------------------------------------------------------------------------
__global__ __launch_bounds__(256) void scatter_transpose(
    const float* __restrict__ W, unsigned short* __restrict__ Wt,
    const int* __restrict__ r0, const int* __restrict__ c0, const float* __restrict__ v0,
    const int* __restrict__ r1, const int* __restrict__ c1, const float* __restrict__ v1,
    unsigned long long* __restrict__ stg, unsigned short* __restrict__ dir) {
    const int t = threadIdx.x;
    if (blockIdx.x < kTransBlocks) {
        const int e = blockIdx.x * 256 + t;
        const int n = e & 127, k = e >> 7;
        Wt[n * 128 + k] = f32_to_bf16(W[e]);
        return;
    }

    __shared__ unsigned long long recs[kChunk];   // 56 KB
    __shared__ int hist[kDirStride];
    __shared__ int cur[kDirStride];
    __shared__ int sc2[256];

    const int b = blockIdx.x - kTransBlocks;      // 0..447
    const bool m1 = b >= kChunkBlocks;
    const int cb = m1 ? b - kChunkBlocks : b;
    const int* rows = m1 ? r1 : r0;
    const int* cols = m1 ? c1 : c0;
    const float* vals = m1 ? v1 : v0;
    unsigned long long* dst = stg + (size_t)b * kChunk;      // block-contiguous
    unsigned short* dirm = dir + (size_t)b * kDirStride;

    for (int i = t; i < kDirStride; i += 256) hist[i] = 0;
    __syncthreads();

    const int base0 = cb * kChunk;
    const int cnt = min(kNNZ - base0, kChunk);

    // pass 1: histogram by bucket
    for (int j = t; j < cnt; j += 256) atomicAdd(&hist[rows[base0 + j] >> 8], 1);
    __syncthreads();

    // pass 2: scan 392 bins (threads 0..195 own bins 2t, 2t+1)
    int s = 0;
    if (t < 196) s = hist[2 * t] + hist[2 * t + 1];
    sc2[t] = (t < 196) ? s : 0;
    __syncthreads();
    #pragma unroll
    for (int off = 1; off < 256; off <<= 1) {
        const int add = (t >= off) ? sc2[t - off] : 0;
        __syncthreads();
        sc2[t] += add;
        __syncthreads();
    }
    if (t < 196) {
        const int ex = sc2[t] - s;
        cur[2 * t] = ex;
        cur[2 * t + 1] = ex + hist[2 * t];
        dirm[2 * t] = (unsigned short)ex;
        dirm[2 * t + 1] = (unsigned short)(ex + hist[2 * t]);
    }
    __syncthreads();

    // pass 3: place records grouped by bucket in LDS
    for (int j = t; j < cnt; j += 256) {
        const int idx = base0 + j;
        const int r = rows[idx];
        const int bk = r >> 8;
        const int pos = atomicAdd(&cur[bk], 1);
        const unsigned int key = ((unsigned int)(r & 255) << 17) | (unsigned int)cols[idx];
        recs[pos] = ((unsigned long long)__float_as_uint(vals[idx]) << 32) | key;
    }
    __syncthreads();

    // pass 4: flush, perfectly coalesced
    for (int j = t; j < cnt; j += 256) dst[j] = recs[j];
}

// ---------------------------------------------------------------------------
// Dispatch 2: GEMM X'(bf16) = x @ W via mfma_f32_16x16x32_bf16 (r2-r10).
// ---------------------------------------------------------------------------
__global__ __launch_bounds__(256) void gemm_mfma(const float* __restrict__ x,
                                                 const unsigned short* __restrict__ Wt,
                                                 unsigned short* __restrict__ Xpb) {
    __shared__ __align__(16) unsigned short xs[64 * 128];   // 16 KB
    const int t = threadIdx.x;
    const int rowBase = blockIdx.x * 64;

    {
        const int lrow = t >> 2;
        const int q = t & 3;
        int srow = rowBase + lrow;
        if (srow >= kN) srow = kN - 1;
        const float4* xr = (const float4*)(x + (size_t)srow * kF) + q * 8;
        #pragma unroll
        for (int i = 0; i < 8; ++i) {
            const float4 f = xr[i];
            ushort4v h;
            h.x = f32_to_bf16(f.x); h.y = f32_to_bf16(f.y);
            h.z = f32_to_bf16(f.z); h.w = f32_to_bf16(f.w);
            const int kidx = q * 32 + i * 4;
            *(ushort4v*)&xs[lrow * 128 + (kidx ^ ((lrow & 7) << 3))] = h;
        }
    }
    __syncthreads();

    const int w = t >> 6;
    const int l = t & 63;
    const int lr = l & 15;
    const int lq = l >> 4;

    f32x4 acc[8];
    #pragma unroll
    for (int n = 0; n < 8; ++n) acc[n] = (f32x4){0.f, 0.f, 0.f, 0.f};

    const int arow = w * 16 + lr;
    #pragma unroll
    for (int ks = 0; ks < 4; ++ks) {
        const int akidx = ks * 32 + lq * 8;
        const bf16x8 a = *(const bf16x8*)&xs[arow * 128 + (akidx ^ ((arow & 7) << 3))];
        #pragma unroll
        for (int n = 0; n < 8; ++n) {
            const int bn = n * 16 + lr;
            const bf16x8 b = *(const bf16x8*)(Wt + bn * 128 + akidx);  // global, L1
            acc[n] = __builtin_amdgcn_mfma_f32_16x16x32_bf16(a, b, acc[n], 0, 0, 0);
        }
    }

    #pragma unroll
    for (int j = 0; j < 4; ++j) {
        const int row = rowBase + w * 16 + lq * 4 + j;
        if (row < kN) {
            unsigned short* orow = Xpb + (size_t)row * kF + lr;
            #pragma unroll
            for (int n = 0; n < 8; ++n) orow[n * 16] = f32_to_bf16(acc[n][j]);
        }
    }
}

// ---------------------------------------------------------------------------
// Dispatch 3: bucket_sort — 512 threads per bucket, both matrices (782 blks).
// Reads runs via dir, LDS counting-sort by local row, flush sorted records
// to sortedG (coalesced) + absolute [rs,re) per row.
// LDS: 36.9KB sorted + ~4.8KB tables.
// ---------------------------------------------------------------------------
__global__ __launch_bounds__(512) void bucket_sort(
    const unsigned long long* __restrict__ stg,
    const unsigned short* __restrict__ dir,
    unsigned long long* __restrict__ sortedG,
    int* __restrict__ rs, int* __restrict__ re) {
    __shared__ unsigned long long sorted[kBucketCap];   // 36.9 KB
    __shared__ int rlen[kChunkBlocks];                  // 224
    __shared__ int gst[kChunkBlocks];
    __shared__ int hist[256];
    __shared__ int sc[256];
    __shared__ int cur[256];

    const int bidx = blockIdx.x;
    const bool m1 = bidx >= kBuckets;
    const int bk = m1 ? bidx - kBuckets : bidx;
    const int t = threadIdx.x;
    const unsigned long long* stgm = stg + (m1 ? (size_t)kSlotsPerMat : 0);

    if (t < kChunkBlocks) {
        const unsigned short* dd =
            dir + (size_t)((m1 ? kChunkBlocks : 0) + t) * kDirStride;
        const int s = dd[bk];
        rlen[t] = dd[bk + 1] - s;
        gst[t] = t * kChunk + s;
    }
    if (t < 256) hist[t] = 0;
    __syncthreads();

    const int g = t >> 5;        // 16 groups of 32 lanes
    const int lane = t & 31;

    // histogram by local row
    for (int blk = g; blk < kChunkBlocks; blk += 16) {
        const int len = rlen[blk];
        const int gs = gst[blk];
        for (int i = lane; i < len; i += 32) {
            const unsigned int lo = (unsigned int)stgm[gs + i];
            atomicAdd(&hist[(lo >> 17) & 255], 1);
        }
    }
    __syncthreads();

    // scan 256 bins
    const int v = (t < 256) ? hist[t] : 0;
    if (t < 256) sc[t] = v;
    __syncthreads();
    #pragma unroll
    for (int off = 1; off < 256; off <<= 1) {
        const int add = (t < 256 && t >= off) ? sc[t - off] : 0;
        __syncthreads();
        if (t < 256) sc[t] += add;
        __syncthreads();
    }
    if (t < 256) cur[t] = sc[t] - v;   // exclusive
    __syncthreads();

    // place sorted by local row
    for (int blk = g; blk < kChunkBlocks; blk += 16) {
        const int len = rlen[blk];
        const int gs = gst[blk];
        for (int i = lane; i < len; i += 32) {
            const unsigned long long p = stgm[gs + i];
            const int lrow = (int)(((unsigned int)p >> 17) & 255);
            sorted[atomicAdd(&cur[lrow], 1)] = p;
        }
    }
    __syncthreads();

    // flush + bounds
    const int nrec = sc[255];
    const size_t outBase = (size_t)bidx * kBucketCap;
    for (int j = t; j < nrec; j += 512) sortedG[outBase + j] = sorted[j];
    if (t < 256) {
        const int row = bk * 256 + t;
        if (row < kN) {
            const int rg = (m1 ? kN : 0) + row;
            rs[rg] = (int)outBase + sc[t] - hist[t];
            re[rg] = (int)outBase + sc[t];
        }
    }
}

// ---------------------------------------------------------------------------
// Dispatch 4/5: row-parallel gather SpMM (r7-proven). 32 lanes per row,
// coalesced rec load per 32-edge chunk, shuffle-broadcast, 4-wide bf16
// gathers, f32 accumulate. Fused scale / relu; bf16 or f32 output.
// ---------------------------------------------------------------------------
template <bool ROW_SCALE, bool RELU, bool OUT_BF16>
__global__ __launch_bounds__(256) void spmm_csr(const int* __restrict__ rs,
                                                const int* __restrict__ re,
                                                const unsigned long long* __restrict__ rec,
                                                const float* __restrict__ scale,
                                                const unsigned short* __restrict__ Xin,
                                                void* __restrict__ Xout) {
    const int tid = blockIdx.x * 256 + threadIdx.x;
    const int r = tid >> 5;          // grid = kN*32/256 exactly
    const int lane = tid & 31;

    const int s = rs[r];
    const int e = re[r];

    float4 acc = make_float4(0.f, 0.f, 0.f, 0.f);

    for (int base = s; base < e; base += 32) {
        int cl = 0;
        float vl = 0.f;
        if (base + lane < e) {
            const unsigned long long p = rec[base + lane];
            cl = (int)((unsigned int)p & 0x1FFFF);
            vl = __uint_as_float((unsigned int)(p >> 32));
        }
        const int m4 = (min(32, e - base) + 3) & ~3;
        for (int j = 0; j < m4; j += 4) {
            const int c0 = __shfl(cl, j, 32);
            const int c1 = __shfl(cl, j + 1, 32);
            const int c2 = __shfl(cl, j + 2, 32);
            const int c3 = __shfl(cl, j + 3, 32);
            const float w0 = __shfl(vl, j, 32);
            const float w1 = __shfl(vl, j + 1, 32);
            const float w2 = __shfl(vl, j + 2, 32);
            const float w3 = __shfl(vl, j + 3, 32);
            const ushort4v x0 = *(const ushort4v*)(Xin + (size_t)c0 * kF + lane * 4);
            const ushort4v x1 = *(const ushort4v*)(Xin + (size_t)c1 * kF + lane * 4);
            const ushort4v x2 = *(const ushort4v*)(Xin + (size_t)c2 * kF + lane * 4);
            const ushort4v x3 = *(const ushort4v*)(Xin + (size_t)c3 * kF + lane * 4);
            acc.x = fmaf(w0, bf16_to_f32(x0.x), acc.x);
            acc.y = fmaf(w0, bf16_to_f32(x0.y), acc.y);
            acc.z = fmaf(w0, bf16_to_f32(x0.z), acc.z);
            acc.w = fmaf(w0, bf16_to_f32(x0.w), acc.w);
            acc.x = fmaf(w1, bf16_to_f32(x1.x), acc.x);
            acc.y = fmaf(w1, bf16_to_f32(x1.y), acc.y);
            acc.z = fmaf(w1, bf16_to_f32(x1.z), acc.z);
            acc.w = fmaf(w1, bf16_to_f32(x1.w), acc.w);
            acc.x = fmaf(w2, bf16_to_f32(x2.x), acc.x);
            acc.y = fmaf(w2, bf16_to_f32(x2.y), acc.y);
            acc.z = fmaf(w2, bf16_to_f32(x2.z), acc.z);
            acc.w = fmaf(w2, bf16_to_f32(x2.w), acc.w);
            acc.x = fmaf(w3, bf16_to_f32(x3.x), acc.x);
            acc.y = fmaf(w3, bf16_to_f32(x3.y), acc.y);
            acc.z = fmaf(w3, bf16_to_f32(x3.z), acc.z);
            acc.w = fmaf(w3, bf16_to_f32(x3.w), acc.w);
        }
    }
    if (ROW_SCALE) {
        const float k = scale[r];
        acc.x *= k; acc.y *= k; acc.z *= k; acc.w *= k;
    }
    if (RELU) {
        acc.x = fmaxf(acc.x, 0.f); acc.y = fmaxf(acc.y, 0.f);
        acc.z = fmaxf(acc.z, 0.f); acc.w = fmaxf(acc.w, 0.f);
    }
    if (OUT_BF16) {
        ushort4v o;
        o.x = f32_to_bf16(acc.x); o.y = f32_to_bf16(acc.y);
        o.z = f32_to_bf16(acc.z); o.w = f32_to_bf16(acc.w);
        *(ushort4v*)((unsigned short*)Xout + (size_t)r * kF + lane * 4) = o;
    } else {
        ((float4*)Xout)[(size_t)r * 32 + lane] = acc;
    }
}

extern "C" void kernel_launch(void* const* d_in, const int* in_sizes, int n_in,
                              void* d_out, int out_size, void* d_ws, size_t ws_size,
                              hipStream_t stream) {
    const float* x    = (const float*)d_in[0];
    const float* W    = (const float*)d_in[1];
    const float* kern = (const float*)d_in[2];
    const int*   p0r  = (const int*)d_in[3];
    const int*   p0c  = (const int*)d_in[4];
    const float* p0v  = (const float*)d_in[5];
    const int*   p1r  = (const int*)d_in[6];
    const int*   p1c  = (const int*)d_in[7];
    const float* p1v  = (const float*)d_in[8];

    // raw record staging lives in d_out (25.7 MB of its 51.2 MB); it is dead
    // after bucket_sort, and spmm #5 fully overwrites d_out with the output.
    unsigned long long* stg = (unsigned long long*)d_out;

    // ws layout (16B-aligned slabs), total ~82 MB
    char* w = (char*)d_ws;
    size_t off = 0;
    unsigned short* Xpb = (unsigned short*)(w + off); off += (size_t)kN * kF * 2; // 25.6 MB
    unsigned short* Xtb = (unsigned short*)(w + off); off += (size_t)kN * kF * 2; // 25.6 MB
    unsigned short* Wt = (unsigned short*)(w + off);  off += 128 * 128 * 2;       // 32 KB
    unsigned short* dir = (unsigned short*)(w + off);
    off += (size_t)2 * kChunkBlocks * kDirStride * 2;                             // 351 KB
    off = (off + 15) & ~(size_t)15;
    unsigned long long* sortedG = (unsigned long long*)(w + off);
    off += (size_t)2 * kBuckets * kBucketCap * 8;                                 // 28.8 MB
    int* rs = (int*)(w + off);                        off += (size_t)2 * kN * 4;  // 0.8 MB
    int* re = (int*)(w + off);                        off += (size_t)2 * kN * 4;  // 0.8 MB

    // 1) Wt = bf16(W^T)  ||  bucket both edge lists (coalesced, block-contig)
    scatter_transpose<<<kTransBlocks + 2 * kChunkBlocks, 256, 0, stream>>>(
        W, Wt, p0r, p0c, p0v, p1r, p1c, p1v, stg, dir);

    // 2) X'(bf16) = x @ W
    gemm_mfma<<<kGemmBlocks, 256, 0, stream>>>(x, Wt, Xpb);

    // 3) sort both matrices to exact row order (sortedG + absolute [rs,re))
    bucket_sort<<<2 * kBuckets, 512, 0, stream>>>(stg, dir, sortedG, rs, re);

    // 4) Xt(bf16) = kernel * (phi0 @ X')
    spmm_csr<true, false, true><<<kRowBlocks, 256, 0, stream>>>(
        rs, re, sortedG, kern, Xpb, Xtb);

    // 5) out(f32) = relu(phi1 @ Xt)
    spmm_csr<false, true, false><<<kRowBlocks, 256, 0, stream>>>(
        rs + kN, re + kN, sortedG, nullptr, Xtb, (float*)d_out);
}

// Round 13
// 207.311 us; speedup vs baseline: 1.1198x; 1.0334x over previous
//
#include <hip/hip_runtime.h>

// Wavelet_Convolution: out = relu(phi1 @ (kernel * (phi0 @ (x @ W))))
// N=100000, F=128, NNZ=1.6M per sparse matrix (COO, int32 idx, f32 vals).
//
// Pipeline (4 dispatches):
//   1) scatter_transpose: [blocks 0..63] Wt = bf16(W^T);
//      [rest] per 7168-edge chunk: group records by 256-row bucket in LDS,
//      flush block-contiguous into d_out-as-scratch (fully coalesced).
//      Run directory (u16) per (chunk,bucket).
//   2) sort_gemm (fused, independent work):
//      [blocks 0..781]   bucket_sort both matrices: gather runs, LDS
//                        counting-sort by row, flush sorted + [rs,re)
//      [blocks 782..1563] X'(bf16) = x @ W (MFMA, 128 rows/block, 8 waves)
//   3) spmm_csr: Xt(bf16) = kernel * (phi0 @ X')  — row-parallel gather
//   4) spmm_csr: out(f32) = relu(phi1 @ Xt) — overwrites dead scratch.

constexpr int kN = 100000;
constexpr int kF = 128;
constexpr int kNNZ = 1600000;

constexpr int kBuckets = (kN + 255) / 256;                  // 391 (256-row buckets)
constexpr int kBucketCap = 4608;                            // mean 4096 + 8 sigma
constexpr int kChunk = 7168;                                // edges per scatter block
constexpr int kChunkBlocks = (kNNZ + kChunk - 1) / kChunk;  // 224 per matrix
constexpr int kSlotsPerMat = kChunkBlocks * kChunk;         // 1,605,632
constexpr int kDirStride = kBuckets + 1;                    // 392 entries per chunk
constexpr int kTransBlocks = 64;
constexpr int kSortBlocks = 2 * kBuckets;                   // 782
constexpr int kGemmBlocks = (kN + 127) / 128;               // 782 (128 rows, 512 thr)
constexpr int kRowBlocks = kN * 32 / 256;                   // 12500

typedef short bf16x8 __attribute__((ext_vector_type(8)));
typedef float f32x4 __attribute__((ext_vector_type(4)));
typedef unsigned short ushort4v __attribute__((ext_vector_type(4)));

__device__ __forceinline__ unsigned short f32_to_bf16(float f) {
    unsigned int u = __float_as_uint(f);
    u += 0x7fffu + ((u >> 16) & 1u);   // round-to-nearest-even
    return (unsigned short)(u >> 16);
}
__device__ __forceinline__ float bf16_to_f32(unsigned short h) {
    return __uint_as_float((unsigned int)h << 16);
}

// ---------------------------------------------------------------------------
// Dispatch 1: W transpose (blocks 0..63) + coalesced bucket scatter (rest).
// Record: hi32 = f32 val, lo32 = (localrow&255)<<17 | col (col < 2^17).
// ---------------------------------------------------------------------------
__global__ __launch_bounds__(256) void scatter_transpose(
    const float* __restrict__ W, unsigned short* __restrict__ Wt,
    const int* __restrict__ r0, const int* __restrict__ c0, const float* __restrict__ v0,
    const int* __restrict__ r1, const int* __restrict__ c1, const float* __restrict__ v1,
    unsigned long long* __restrict__ stg, unsigned short* __restrict__ dir) {
    const int t = threadIdx.x;
    if (blockIdx.x < kTransBlocks) {
        const int e = blockIdx.x * 256 + t;
        const int n = e & 127, k = e >> 7;
        Wt[n * 128 + k] = f32_to_bf16(W[e]);
        return;
    }

    __shared__ unsigned long long recs[kChunk];   // 56 KB
    __shared__ int hist[kDirStride];
    __shared__ int cur[kDirStride];
    __shared__ int sc2[256];

    const int b = blockIdx.x - kTransBlocks;      // 0..447
    const bool m1 = b >= kChunkBlocks;
    const int cb = m1 ? b - kChunkBlocks : b;
    const int* rows = m1 ? r1 : r0;
    const int* cols = m1 ? c1 : c0;
    const float* vals = m1 ? v1 : v0;
    unsigned long long* dst = stg + (size_t)b * kChunk;      // block-contiguous
    unsigned short* dirm = dir + (size_t)b * kDirStride;

    for (int i = t; i < kDirStride; i += 256) hist[i] = 0;
    __syncthreads();

    const int base0 = cb * kChunk;
    const int cnt = min(kNNZ - base0, kChunk);

    for (int j = t; j < cnt; j += 256) atomicAdd(&hist[rows[base0 + j] >> 8], 1);
    __syncthreads();

    // scan 392 bins (threads 0..195 own bins 2t, 2t+1)
    int s = 0;
    if (t < 196) s = hist[2 * t] + hist[2 * t + 1];
    sc2[t] = (t < 196) ? s : 0;
    __syncthreads();
    #pragma unroll
    for (int off = 1; off < 256; off <<= 1) {
        const int add = (t >= off) ? sc2[t - off] : 0;
        __syncthreads();
        sc2[t] += add;
        __syncthreads();
    }
    if (t < 196) {
        const int ex = sc2[t] - s;
        cur[2 * t] = ex;
        cur[2 * t + 1] = ex + hist[2 * t];
        dirm[2 * t] = (unsigned short)ex;
        dirm[2 * t + 1] = (unsigned short)(ex + hist[2 * t]);
    }
    __syncthreads();

    for (int j = t; j < cnt; j += 256) {
        const int idx = base0 + j;
        const int r = rows[idx];
        const int bk = r >> 8;
        const int pos = atomicAdd(&cur[bk], 1);
        const unsigned int key = ((unsigned int)(r & 255) << 17) | (unsigned int)cols[idx];
        recs[pos] = ((unsigned long long)__float_as_uint(vals[idx]) << 32) | key;
    }
    __syncthreads();

    for (int j = t; j < cnt; j += 256) dst[j] = recs[j];
}

// ---------------------------------------------------------------------------
// Dispatch 2 (fused): bucket_sort (blocks 0..781) || gemm (blocks 782..1563).
// LDS union: sort 41.7 KB | gemm 32 KB -> 3 blocks/CU for both branches.
// ---------------------------------------------------------------------------
__global__ __launch_bounds__(512) void sort_gemm(
    // sort inputs
    const unsigned long long* __restrict__ stg,
    const unsigned short* __restrict__ dir,
    unsigned long long* __restrict__ sortedG,
    int* __restrict__ rs, int* __restrict__ re,
    // gemm inputs
    const float* __restrict__ x, const unsigned short* __restrict__ Wt,
    unsigned short* __restrict__ Xpb) {
    __shared__ __align__(16) char smem[41728];
    const int t = threadIdx.x;

    if (blockIdx.x < kSortBlocks) {
        // ================= sort branch =================
        unsigned long long* sorted = (unsigned long long*)smem;       // 36864 B
        int* rlen = (int*)(smem + 36864);                             // 896 B
        int* gst  = (int*)(smem + 36864 + 896);                       // 896 B
        int* hist = (int*)(smem + 36864 + 1792);                      // 1024 B
        int* sc   = (int*)(smem + 36864 + 2816);                      // 1024 B
        int* cur  = (int*)(smem + 36864 + 3840);                      // 1024 B

        const int bidx = blockIdx.x;
        const bool m1 = bidx >= kBuckets;
        const int bk = m1 ? bidx - kBuckets : bidx;
        const unsigned long long* stgm = stg + (m1 ? (size_t)kSlotsPerMat : 0);

        if (t < kChunkBlocks) {
            const unsigned short* dd =
                dir + (size_t)((m1 ? kChunkBlocks : 0) + t) * kDirStride;
            const int s = dd[bk];
            rlen[t] = dd[bk + 1] - s;
            gst[t] = t * kChunk + s;
        }
        if (t < 256) hist[t] = 0;
        __syncthreads();

        const int g = t >> 5;        // 16 groups of 32 lanes
        const int lane = t & 31;

        for (int blk = g; blk < kChunkBlocks; blk += 16) {
            const int len = rlen[blk];
            const int gs = gst[blk];
            for (int i = lane; i < len; i += 32) {
                const unsigned int lo = (unsigned int)stgm[gs + i];
                atomicAdd(&hist[(lo >> 17) & 255], 1);
            }
        }
        __syncthreads();

        const int v = (t < 256) ? hist[t] : 0;
        if (t < 256) sc[t] = v;
        __syncthreads();
        #pragma unroll
        for (int off = 1; off < 256; off <<= 1) {
            const int add = (t < 256 && t >= off) ? sc[t - off] : 0;
            __syncthreads();
            if (t < 256) sc[t] += add;
            __syncthreads();
        }
        if (t < 256) cur[t] = sc[t] - v;   // exclusive
        __syncthreads();

        for (int blk = g; blk < kChunkBlocks; blk += 16) {
            const int len = rlen[blk];
            const int gs = gst[blk];
            for (int i = lane; i < len; i += 32) {
                const unsigned long long p = stgm[gs + i];
                const int lrow = (int)(((unsigned int)p >> 17) & 255);
                sorted[atomicAdd(&cur[lrow], 1)] = p;
            }
        }
        __syncthreads();

        const int nrec = sc[255];
        const size_t outBase = (size_t)bidx * kBucketCap;
        for (int j = t; j < nrec; j += 512) sortedG[outBase + j] = sorted[j];
        if (t < 256) {
            const int row = bk * 256 + t;
            if (row < kN) {
                const int rg = (m1 ? kN : 0) + row;
                rs[rg] = (int)outBase + sc[t] - hist[t];
                re[rg] = (int)outBase + sc[t];
            }
        }
    } else {
        // ================= gemm branch (128 rows, 8 waves) =================
        unsigned short* xs = (unsigned short*)smem;     // 128x128 bf16 = 32 KB
        const int rowBase = (blockIdx.x - kSortBlocks) * 128;

        {
            const int lrow = t >> 2;                    // 0..127
            const int q = t & 3;
            int srow = rowBase + lrow;
            if (srow >= kN) srow = kN - 1;
            const float4* xr = (const float4*)(x + (size_t)srow * kF) + q * 8;
            #pragma unroll
            for (int i = 0; i < 8; ++i) {
                const float4 f = xr[i];
                ushort4v h;
                h.x = f32_to_bf16(f.x); h.y = f32_to_bf16(f.y);
                h.z = f32_to_bf16(f.z); h.w = f32_to_bf16(f.w);
                const int kidx = q * 32 + i * 4;
                *(ushort4v*)&xs[lrow * 128 + (kidx ^ ((lrow & 7) << 3))] = h;
            }
        }
        __syncthreads();

        const int w = t >> 6;        // wave 0..7 -> rows w*16..w*16+15
        const int l = t & 63;
        const int lr = l & 15;
        const int lq = l >> 4;

        f32x4 acc[8];
        #pragma unroll
        for (int n = 0; n < 8; ++n) acc[n] = (f32x4){0.f, 0.f, 0.f, 0.f};

        const int arow = w * 16 + lr;
        #pragma unroll
        for (int ks = 0; ks < 4; ++ks) {
            const int akidx = ks * 32 + lq * 8;
            const bf16x8 a = *(const bf16x8*)&xs[arow * 128 + (akidx ^ ((arow & 7) << 3))];
            #pragma unroll
            for (int n = 0; n < 8; ++n) {
                const int bn = n * 16 + lr;
                const bf16x8 b = *(const bf16x8*)(Wt + bn * 128 + akidx);  // global, L1
                acc[n] = __builtin_amdgcn_mfma_f32_16x16x32_bf16(a, b, acc[n], 0, 0, 0);
            }
        }

        // C/D layout: col = lr, row = lq*4 + j
        #pragma unroll
        for (int j = 0; j < 4; ++j) {
            const int row = rowBase + w * 16 + lq * 4 + j;
            if (row < kN) {
                unsigned short* orow = Xpb + (size_t)row * kF + lr;
                #pragma unroll
                for (int n = 0; n < 8; ++n) orow[n * 16] = f32_to_bf16(acc[n][j]);
            }
        }
    }
}

// ---------------------------------------------------------------------------
// Dispatch 3/4: row-parallel gather SpMM. 32 lanes per row, coalesced
// nontemporal rec load per 32-edge chunk, shuffle-broadcast, 4-wide bf16
// gathers, f32 accumulate. Fused scale / relu; nontemporal output stores
// (ext_vector types only — clang rejects HIP_vector_type there).
// ---------------------------------------------------------------------------
template <bool ROW_SCALE, bool RELU, bool OUT_BF16>
__global__ __launch_bounds__(256) void spmm_csr(const int* __restrict__ rs,
                                                const int* __restrict__ re,
                                                const unsigned long long* __restrict__ rec,
                                                const float* __restrict__ scale,
                                                const unsigned short* __restrict__ Xin,
                                                void* __restrict__ Xout) {
    const int tid = blockIdx.x * 256 + threadIdx.x;
    const int r = tid >> 5;          // grid = kN*32/256 exactly
    const int lane = tid & 31;

    const int s = rs[r];
    const int e = re[r];

    float4 acc = make_float4(0.f, 0.f, 0.f, 0.f);

    for (int base = s; base < e; base += 32) {
        int cl = 0;
        float vl = 0.f;
        if (base + lane < e) {
            const unsigned long long p = __builtin_nontemporal_load(&rec[base + lane]);
            cl = (int)((unsigned int)p & 0x1FFFF);
            vl = __uint_as_float((unsigned int)(p >> 32));
        }
        const int m4 = (min(32, e - base) + 3) & ~3;
        for (int j = 0; j < m4; j += 4) {
            const int c0 = __shfl(cl, j, 32);
            const int c1 = __shfl(cl, j + 1, 32);
            const int c2 = __shfl(cl, j + 2, 32);
            const int c3 = __shfl(cl, j + 3, 32);
            const float w0 = __shfl(vl, j, 32);
            const float w1 = __shfl(vl, j + 1, 32);
            const float w2 = __shfl(vl, j + 2, 32);
            const float w3 = __shfl(vl, j + 3, 32);
            const ushort4v x0 = *(const ushort4v*)(Xin + (size_t)c0 * kF + lane * 4);
            const ushort4v x1 = *(const ushort4v*)(Xin + (size_t)c1 * kF + lane * 4);
            const ushort4v x2 = *(const ushort4v*)(Xin + (size_t)c2 * kF + lane * 4);
            const ushort4v x3 = *(const ushort4v*)(Xin + (size_t)c3 * kF + lane * 4);
            acc.x = fmaf(w0, bf16_to_f32(x0.x), acc.x);
            acc.y = fmaf(w0, bf16_to_f32(x0.y), acc.y);
            acc.z = fmaf(w0, bf16_to_f32(x0.z), acc.z);
            acc.w = fmaf(w0, bf16_to_f32(x0.w), acc.w);
            acc.x = fmaf(w1, bf16_to_f32(x1.x), acc.x);
            acc.y = fmaf(w1, bf16_to_f32(x1.y), acc.y);
            acc.z = fmaf(w1, bf16_to_f32(x1.z), acc.z);
            acc.w = fmaf(w1, bf16_to_f32(x1.w), acc.w);
            acc.x = fmaf(w2, bf16_to_f32(x2.x), acc.x);
            acc.y = fmaf(w2, bf16_to_f32(x2.y), acc.y);
            acc.z = fmaf(w2, bf16_to_f32(x2.z), acc.z);
            acc.w = fmaf(w2, bf16_to_f32(x2.w), acc.w);
            acc.x = fmaf(w3, bf16_to_f32(x3.x), acc.x);
            acc.y = fmaf(w3, bf16_to_f32(x3.y), acc.y);
            acc.z = fmaf(w3, bf16_to_f32(x3.z), acc.z);
            acc.w = fmaf(w3, bf16_to_f32(x3.w), acc.w);
        }
    }
    if (ROW_SCALE) {
        const float k = scale[r];
        acc.x *= k; acc.y *= k; acc.z *= k; acc.w *= k;
    }
    if (RELU) {
        acc.x = fmaxf(acc.x, 0.f); acc.y = fmaxf(acc.y, 0.f);
        acc.z = fmaxf(acc.z, 0.f); acc.w = fmaxf(acc.w, 0.f);
    }
    if (OUT_BF16) {
        ushort4v o;
        o.x = f32_to_bf16(acc.x); o.y = f32_to_bf16(acc.y);
        o.z = f32_to_bf16(acc.z); o.w = f32_to_bf16(acc.w);
        __builtin_nontemporal_store(
            o, (ushort4v*)((unsigned short*)Xout + (size_t)r * kF + lane * 4));
    } else {
        f32x4 o;
        o.x = acc.x; o.y = acc.y; o.z = acc.z; o.w = acc.w;
        __builtin_nontemporal_store(o, (f32x4*)Xout + (size_t)r * 32 + lane);
    }
}

extern "C" void kernel_launch(void* const* d_in, const int* in_sizes, int n_in,
                              void* d_out, int out_size, void* d_ws, size_t ws_size,
                              hipStream_t stream) {
    const float* x    = (const float*)d_in[0];
    const float* W    = (const float*)d_in[1];
    const float* kern = (const float*)d_in[2];
    const int*   p0r  = (const int*)d_in[3];
    const int*   p0c  = (const int*)d_in[4];
    const float* p0v  = (const float*)d_in[5];
    const int*   p1r  = (const int*)d_in[6];
    const int*   p1c  = (const int*)d_in[7];
    const float* p1v  = (const float*)d_in[8];

    // raw record staging lives in d_out (25.7 MB of its 51.2 MB); dead after
    // sort_gemm, and dispatch 4 fully overwrites d_out with the output.
    unsigned long long* stg = (unsigned long long*)d_out;

    // ws layout (16B-aligned slabs), total ~82 MB
    char* w = (char*)d_ws;
    size_t off = 0;
    unsigned short* Xpb = (unsigned short*)(w + off); off += (size_t)kN * kF * 2; // 25.6 MB
    unsigned short* Xtb = (unsigned short*)(w + off); off += (size_t)kN * kF * 2; // 25.6 MB
    unsigned short* Wt = (unsigned short*)(w + off);  off += 128 * 128 * 2;       // 32 KB
    unsigned short* dir = (unsigned short*)(w + off);
    off += (size_t)2 * kChunkBlocks * kDirStride * 2;                             // 351 KB
    off = (off + 15) & ~(size_t)15;
    unsigned long long* sortedG = (unsigned long long*)(w + off);
    off += (size_t)2 * kBuckets * kBucketCap * 8;                                 // 28.8 MB
    int* rs = (int*)(w + off);                        off += (size_t)2 * kN * 4;  // 0.8 MB
    int* re = (int*)(w + off);                        off += (size_t)2 * kN * 4;  // 0.8 MB

    // 1) Wt = bf16(W^T)  ||  bucket both edge lists (coalesced, block-contig)
    scatter_transpose<<<kTransBlocks + 2 * kChunkBlocks, 256, 0, stream>>>(
        W, Wt, p0r, p0c, p0v, p1r, p1c, p1v, stg, dir);

    // 2) sort both matrices  ||  X'(bf16) = x @ W
    sort_gemm<<<kSortBlocks + kGemmBlocks, 512, 0, stream>>>(
        stg, dir, sortedG, rs, re, x, Wt, Xpb);

    // 3) Xt(bf16) = kernel * (phi0 @ X')
    spmm_csr<true, false, true><<<kRowBlocks, 256, 0, stream>>>(
        rs, re, sortedG, kern, Xpb, Xtb);

    // 4) out(f32) = relu(phi1 @ Xt)
    spmm_csr<false, true, false><<<kRowBlocks, 256, 0, stream>>>(
        rs + kN, re + kN, sortedG, nullptr, Xtb, (float*)d_out);
}